// Round 4
// baseline (34394.870 us; speedup 1.0000x reference)
//
#include <hip/hip_runtime.h>
#include <stdint.h>

// ---------------- problem constants ----------------
#define B_   64
#define S_   1024
#define D_   512
#define H_   1024
#define G_   4096
#define NWG  256

using bf16x8 = __attribute__((ext_vector_type(8))) short;   // 8 bf16 = 4 VGPRs
using f32x16 = __attribute__((ext_vector_type(16))) float;  // MFMA 32x32 acc

// ---------------- ws byte layout ----------------
// [0,2048)      8 group arrival counters, 256B apart (monotone)
// [2048,2052)   top-level counter (monotone)
// [2176,2180)   barrier gen (monotone)
// [4096,528384) h ring: 4 slots (layer0 p0/p1, layer1 p0/p1), 128KB each,
//               slot layout: [ks(64)][mt(2)][lane(64)][j(8)] bf16  (A-fragment order)
// [532480,565248) bsum: 2 layers * 4096 f32  (b_ih + b_hh)
// [1MB, ~29MB)  B-fragments per WG (bf16, MFMA B-operand order)
#define GRP_OFF   0
#define TOP_OFF   2048
#define GEN_OFF   2176
#define RING_OFF  4096
#define SLOT_BYTES 131072
#define BSUM_OFF  532480
#define BFRAG_OFF 1048576
#define B0_PER_WG 98304                        // 96 ksteps * 1KB
#define B1_OFF    (BFRAG_OFF + 128*B0_PER_WG)  // 13631488
#define B1_PER_WG 131072                       // 128 ksteps * 1KB

// LDS layout: [0,131072) staged B-fragments ; [131072, 147968) red[2][64][33]
#define BLDS_BYTES 131072
#define SMEM_TOTAL 147968

// d_out float offsets: out[B,S,H] | c_out[B,S,H] | h1[B,H] | c1[B,H]
#define COUT_OFF 67108864ll
#define HF_OFF   134217728ll
#define CF_OFF   134283264ll

__device__ __forceinline__ uint16_t f2bf(float f) {
  uint32_t u = __float_as_uint(f);
  u += 0x7FFFu + ((u >> 16) & 1u);   // round-to-nearest-even
  return (uint16_t)(u >> 16);
}
__device__ __forceinline__ float sigf(float x)  { return 1.0f / (1.0f + __expf(-x)); }
__device__ __forceinline__ float tanhf_(float x){ return 2.0f / (1.0f + __expf(-2.0f * x)) - 1.0f; }

// ---------------- prep: zero barrier+ring, compute bias sums ----------------
__global__ void prep_misc(const float* __restrict__ bih0, const float* __restrict__ bhh0,
                          const float* __restrict__ bih1, const float* __restrict__ bhh1,
                          char* __restrict__ ws) {
  int tid = blockIdx.x * 256 + threadIdx.x;
  if (tid < 132096) { ((uint32_t*)ws)[tid] = 0u; return; }  // zero [0, 528384)
  int i = tid - 132096;
  if (i < 8192) {
    int L = i >> 12, g = i & 4095;
    float v = L ? (bih1[g] + bhh1[g]) : (bih0[g] + bhh0[g]);
    ((float*)(ws + BSUM_OFF))[L * 4096 + g] = v;
  }
}

// ---------------- prep: pack weights into per-WG MFMA B-fragment order ----------------
// B[k][n] for mfma_32x32x16: lane l holds n=l&31, k=16*ks + 8*(l>>5) + j (j=0..7)
// WG cw owns gate columns n -> global row = (n>>3)*1024 + cw*8 + (n&7)   (i,f,g,o blocks)
__global__ void prep_w(const float* __restrict__ Wih0, const float* __restrict__ Whh0,
                       const float* __restrict__ Wih1, const float* __restrict__ Whh1,
                       char* __restrict__ ws) {
  int tid = blockIdx.x * 256 + threadIdx.x;       // one u32 = 2 bf16 (j, j+1)
  if (tid >= 7340032) return;
  uint32_t* dst = (uint32_t*)(ws + BFRAG_OFF);
  int layer, wg, ks, lane, jp;
  if (tid < 3145728) { layer = 0; wg = tid / 24576; int rem = tid % 24576; ks = rem >> 8; int r2 = rem & 255; lane = r2 >> 2; jp = r2 & 3; }
  else { int t2 = tid - 3145728; layer = 1; wg = t2 / 32768; int rem = t2 % 32768; ks = rem >> 8; int r2 = rem & 255; lane = r2 >> 2; jp = r2 & 3; }
  int n = lane & 31;
  int row = (n >> 3) * 1024 + wg * 8 + (n & 7);
  int k = ks * 16 + ((lane >> 5) << 3) + jp * 2;
  float w0, w1;
  if (!layer) {   // K = 512 (x via W_ih0) then 1024 (h0 via W_hh0)
    if (k < 512) { w0 = Wih0[row * 512 + k];          w1 = Wih0[row * 512 + k + 1]; }
    else         { w0 = Whh0[row * 1024 + k - 512];   w1 = Whh0[row * 1024 + k - 511]; }
  } else {        // K = 1024 (h0 via W_ih1) then 1024 (h1 via W_hh1)
    if (k < 1024){ w0 = Wih1[row * 1024 + k];         w1 = Wih1[row * 1024 + k + 1]; }
    else         { w0 = Whh1[row * 1024 + k - 1024];  w1 = Whh1[row * 1024 + k - 1023]; }
  }
  dst[tid] = (uint32_t)f2bf(w0) | ((uint32_t)f2bf(w1) << 16);
}

// ---------------- prep: x -> bf16 A-fragment layout, overlaid in c_out[0:16, t, :] ----
// xA[t] = 16384 u32; slab lives at c_out[b_ov][t][:] for b_ov=0..15 (written as c_out
// only at interval t+1, after xA[t] is consumed at interval t -> barrier-ordered, safe)
__global__ void prep_x(const float* __restrict__ x, float* __restrict__ out) {
  int tid = blockIdx.x * 256 + threadIdx.x;
  if (tid >= 16777216) return;
  int t = tid >> 14;
  int sidx = tid & 16383;
  int jp = sidx & 3;
  int lane = (sidx >> 2) & 63;
  int mtks = sidx >> 8;
  int mt = mtks & 1, ks = mtks >> 1;
  int b = mt * 32 + (lane & 31);
  int k = ks * 16 + ((lane >> 5) << 3) + jp * 2;
  const float* xp = x + ((long)b * S_ + t) * D_ + k;
  uint32_t v = (uint32_t)f2bf(xp[0]) | ((uint32_t)f2bf(xp[1]) << 16);
  ((uint32_t*)(out + COUT_OFF))[(long)(sidx >> 10) * 1048576 + ((long)t << 10) + (sidx & 1023)] = v;
}

// ---------------- main persistent cooperative kernel ----------------
// WGs 0..127: layer0, h0-cols [cw*8, cw*8+8).  WGs 128..255: layer1 (pipelined one step behind).
// B-fragments staged once into LDS. 2x2 wave split (batch-tile mt = wave>>1, K-half kh = wave&1).
// NEW vs R3: hierarchical grid barrier — 8 parallel group counters (32 arrivals each, separate
// cache lines) feeding one 8-arrival top counter. Removes the 256-serialized-RMW single-line
// bottleneck (~25 us/interval). Fence placement identical to verified centralized variant.
__global__ void __launch_bounds__(256) lstm_main(float* __restrict__ out, char* __restrict__ ws) {
  extern __shared__ char smem[];
  float (*red)[64][33] = (float (*)[64][33])(smem + BLDS_BYTES);   // [2][64][33]

  const int tid = threadIdx.x;
  const int lane = tid & 63;
  const int wave = tid >> 6;
  const int wg = blockIdx.x;
  const int layer = wg >> 7;
  const int cw = wg & 127;
  const int mt = wave >> 1;   // batch tile: 0 -> rows 0-31, 1 -> rows 32-63
  const int kh = wave & 1;    // K half

  uint32_t* grp_cnt = (uint32_t*)(ws + GRP_OFF + (size_t)(wg >> 5) * 256);
  uint32_t* top_cnt = (uint32_t*)(ws + TOP_OFF);
  uint32_t* bar_gen = (uint32_t*)(ws + GEN_OFF);
  const float* bsum = (const float*)(ws + BSUM_OFF) + layer * G_;
  const char* bwg = ws + (layer ? (B1_OFF + (size_t)cw * B1_PER_WG)
                                : (BFRAG_OFF + (size_t)cw * B0_PER_WG));
  float* coutF = out + COUT_OFF;

  const int ksteps = layer ? 128 : 96;
  const int ksph = ksteps >> 1;        // per-wave K-steps (K half)

  // ---- stage this WG's B-fragment slice into LDS, once ----
  {
    const int nchunk = ksteps << 6;    // ksteps*1024B / 16B
    for (int i = tid; i < nchunk; i += 256)
      *(bf16x8*)(smem + (size_t)i * 16) = *(const bf16x8*)(bwg + (size_t)i * 16);
  }
  __syncthreads();

  float cst0 = 0.f, cst1 = 0.f;   // cell state: (b=lane, cc=wave) and (b, cc=wave+4)

  for (int t = 0; t <= S_; ++t) {
    if (t) {  // hierarchical grid barrier #t (monotone counters)
      __syncthreads();
      if (tid == 0) {
        __threadfence();   // release this WG's publish stores
        uint32_t prev = __hip_atomic_fetch_add(grp_cnt, 1u, __ATOMIC_RELAXED, __HIP_MEMORY_SCOPE_AGENT);
        if (prev == (uint32_t)(t * 32 - 1)) {     // last of this group's 32 arrivals
          uint32_t p2 = __hip_atomic_fetch_add(top_cnt, 1u, __ATOMIC_RELAXED, __HIP_MEMORY_SCOPE_AGENT);
          if (p2 == (uint32_t)(t * 8 - 1)) {      // last group
            __hip_atomic_store(bar_gen, (uint32_t)t, __ATOMIC_RELEASE, __HIP_MEMORY_SCOPE_AGENT);
          }
        }
        while (__hip_atomic_load(bar_gen, __ATOMIC_RELAXED, __HIP_MEMORY_SCOPE_AGENT) < (uint32_t)t)
          __builtin_amdgcn_s_sleep(1);
        __threadfence();   // invalidate stale lines before ring reads
      }
      __syncthreads();
    }
    const bool active = layer ? (t >= 1) : (t < S_);
    if (active) {
      // ring slots: h0[t-1] parity (t-1)&1 ; h1[t-2] parity t&1
      const char* slotH0 = ws + RING_OFF + (size_t)((t - 1) & 1) * SLOT_BYTES;
      const char* slotH1 = ws + RING_OFF + (size_t)(2 + (t & 1)) * SLOT_BYTES;

      f32x16 acc = {};
#pragma unroll 8
      for (int s = 0; s < ksph; ++s) {
        const int ks = kh * ksph + s;
        const char* ap;
        if (layer == 0) {
          if (ks < 32) {  // x part from overlay
            int si = ((ks * 2 + mt) * 64 + lane) * 4;
            ap = (const char*)(coutF + (((long)(si >> 10)) << 20) + ((long)t << 10) + (si & 1023));
          } else {        // h0[t-1]
            int k2 = ks - 32;
            ap = slotH0 + ((k2 * 2 + mt) * 64 + lane) * 16;
          }
        } else {
          if (ks < 64) {  // h0[t-1]
            ap = slotH0 + ((ks * 2 + mt) * 64 + lane) * 16;
          } else {        // h1[t-2]
            int k2 = ks - 64;
            ap = slotH1 + ((k2 * 2 + mt) * 64 + lane) * 16;
          }
        }
        bf16x8 av = *(const bf16x8*)ap;
        bf16x8 bv = *(const bf16x8*)(smem + (size_t)ks * 1024 + (size_t)lane * 16);
        acc = __builtin_amdgcn_mfma_f32_32x32x16_bf16(av, bv, acc, 0, 0, 0);
      }
      // C/D layout (verified m74/m101): col=lane&31, row=(r&3)+8*(r>>2)+4*(lane>>5)
      const int col = lane & 31;
      const int rbase = 4 * (lane >> 5);
#pragma unroll
      for (int r = 0; r < 16; ++r) {
        int row = (r & 3) + 8 * (r >> 2) + rbase;
        red[kh][mt * 32 + row][col] = acc[r];
      }
      __syncthreads();

      const int b = lane;
      const int bmt = b >> 5;
      char* pub = ws + RING_OFF + (size_t)((layer << 1) + ((layer ? (t - 1) : t) & 1)) * SLOT_BYTES;
#pragma unroll
      for (int r = 0; r < 2; ++r) {
        int cc = wave + 4 * r;
        int hc = cw * 8 + cc;
        float g0 = red[0][b][cc]      + red[1][b][cc]      + bsum[hc];
        float g1 = red[0][b][8 + cc]  + red[1][b][8 + cc]  + bsum[1024 + hc];
        float g2 = red[0][b][16 + cc] + red[1][b][16 + cc] + bsum[2048 + hc];
        float g3 = red[0][b][24 + cc] + red[1][b][24 + cc] + bsum[3072 + hc];
        float cprev = r ? cst1 : cst0;
        float cn = sigf(g1) * cprev + sigf(g0) * tanhf_(g2);
        float hn = sigf(g3) * tanhf_(cn);
        if (r) cst1 = cn; else cst0 = cn;
        // publish h in A-fragment order (cached stores: merged in L2, flushed by barrier fence)
        int ksh = hc >> 4, rem = hc & 15;
        int laned = (b & 31) + ((rem >> 3) << 5);
        ((uint16_t*)pub)[((ksh * 2 + bmt) * 64 + laned) * 8 + (rem & 7)] = f2bf(hn);
        if (layer) {
          long s_ = t - 1;
          long idx = ((long)b << 20) + (s_ << 10) + hc;
          out[idx] = hn;
          out[COUT_OFF + idx] = cn;
          if (s_ == S_ - 1) {
            out[HF_OFF + ((long)b << 10) + hc] = hn;
            out[CF_OFF + ((long)b << 10) + hc] = cn;
          }
        }
      }
      // NOTE: no trailing __syncthreads here — the grid-barrier's leading __syncthreads
      // (next interval) orders red[] reuse; epilogue reads complete before any thread
      // re-enters the MFMA phase. (R3's extra sync removed — redundant serialization.)
    }
  }
}

// ---------------- launch ----------------
extern "C" void kernel_launch(void* const* d_in, const int* in_sizes, int n_in,
                              void* d_out, int out_size, void* d_ws, size_t ws_size,
                              hipStream_t stream) {
  const float* x    = (const float*)d_in[0];
  const float* Wih0 = (const float*)d_in[1];
  const float* Whh0 = (const float*)d_in[2];
  const float* bih0 = (const float*)d_in[3];
  const float* bhh0 = (const float*)d_in[4];
  const float* Wih1 = (const float*)d_in[5];
  const float* Whh1 = (const float*)d_in[6];
  const float* bih1 = (const float*)d_in[7];
  const float* bhh1 = (const float*)d_in[8];
  float* out = (float*)d_out;
  char* ws = (char*)d_ws;

  static bool attr_set = false;
  if (!attr_set) {
    (void)hipFuncSetAttribute((const void*)lstm_main,
                              hipFuncAttributeMaxDynamicSharedMemorySize, SMEM_TOTAL);
    attr_set = true;
  }

  hipLaunchKernelGGL(prep_misc, dim3((140288 + 255) / 256), dim3(256), 0, stream, bih0, bhh0, bih1, bhh1, ws);
  hipLaunchKernelGGL(prep_w,    dim3(7340032 / 256),        dim3(256), 0, stream, Wih0, Whh0, Wih1, Whh1, ws);
  hipLaunchKernelGGL(prep_x,    dim3(16777216 / 256),       dim3(256), 0, stream, x, out);

  void* args[] = { (void*)&out, (void*)&ws };
  hipLaunchCooperativeKernel((void*)lstm_main, dim3(NWG), dim3(256), args, SMEM_TOTAL, stream);
}

// Round 5
// 29813.162 us; speedup vs baseline: 1.1537x; 1.1537x over previous
//
#include <hip/hip_runtime.h>
#include <stdint.h>

// ---------------- problem constants ----------------
#define B_   64
#define S_   1024
#define D_   512
#define H_   1024
#define G_   4096
#define NWG  256

using bf16x8 = __attribute__((ext_vector_type(8))) short;   // 8 bf16 = 4 VGPRs
using f32x16 = __attribute__((ext_vector_type(16))) float;  // MFMA 32x32 acc

// ---------------- ws byte layout ----------------
// [0,2048)      8 group arrival counters, 256B apart (monotone)
// [2048,2052)   top-level counter (monotone)
// [2176,2180)   barrier gen (monotone)
// [4096,528384) h ring: 4 slots (layer0 p0/p1, layer1 p0/p1), 128KB each,
//               slot layout: [ks(64)][mt(2)][lane(64)][j(8)] bf16  (A-fragment order)
// [532480,565248) bsum: 2 layers * 4096 f32  (b_ih + b_hh)
// [1MB, ~29MB)  B-fragments per WG (bf16, MFMA B-operand order)
#define GRP_OFF   0
#define TOP_OFF   2048
#define GEN_OFF   2176
#define RING_OFF  4096
#define SLOT_BYTES 131072
#define BSUM_OFF  532480
#define BFRAG_OFF 1048576
#define B0_PER_WG 98304                        // 96 ksteps * 1KB
#define B1_OFF    (BFRAG_OFF + 128*B0_PER_WG)  // 13631488
#define B1_PER_WG 131072                       // 128 ksteps * 1KB

// LDS layout: [0,131072) staged B-fragments ; [131072, 147968) red[2][64][33]
#define BLDS_BYTES 131072
#define SMEM_TOTAL 147968

// d_out float offsets: out[B,S,H] | c_out[B,S,H] | h1[B,H] | c1[B,H]
#define COUT_OFF 67108864ll
#define HF_OFF   134217728ll
#define CF_OFF   134283264ll

__device__ __forceinline__ uint16_t f2bf(float f) {
  uint32_t u = __float_as_uint(f);
  u += 0x7FFFu + ((u >> 16) & 1u);   // round-to-nearest-even
  return (uint16_t)(u >> 16);
}
__device__ __forceinline__ float sigf(float x)  { return 1.0f / (1.0f + __expf(-x)); }
__device__ __forceinline__ float tanhf_(float x){ return 2.0f / (1.0f + __expf(-2.0f * x)) - 1.0f; }

// agent-scope (sc1) ring access: write-through publish / L2-bypass read.
// Removes the need for buffer_wbl2 / buffer_inv fences in the recurrent loop.
__device__ __forceinline__ void pub2(uint16_t* p, uint16_t v) {
  __hip_atomic_store(p, v, __ATOMIC_RELAXED, __HIP_MEMORY_SCOPE_AGENT);
}
__device__ __forceinline__ bf16x8 ring_ld(const char* p) {
  union { unsigned long long q[2]; bf16x8 v; } u;
  u.q[0] = __hip_atomic_load((const unsigned long long*)p,       __ATOMIC_RELAXED, __HIP_MEMORY_SCOPE_AGENT);
  u.q[1] = __hip_atomic_load((const unsigned long long*)(p + 8), __ATOMIC_RELAXED, __HIP_MEMORY_SCOPE_AGENT);
  return u.v;
}

// ---------------- prep: zero barrier+ring, compute bias sums ----------------
__global__ void prep_misc(const float* __restrict__ bih0, const float* __restrict__ bhh0,
                          const float* __restrict__ bih1, const float* __restrict__ bhh1,
                          char* __restrict__ ws) {
  int tid = blockIdx.x * 256 + threadIdx.x;
  if (tid < 132096) { ((uint32_t*)ws)[tid] = 0u; return; }  // zero [0, 528384)
  int i = tid - 132096;
  if (i < 8192) {
    int L = i >> 12, g = i & 4095;
    float v = L ? (bih1[g] + bhh1[g]) : (bih0[g] + bhh0[g]);
    ((float*)(ws + BSUM_OFF))[L * 4096 + g] = v;
  }
}

// ---------------- prep: pack weights into per-WG MFMA B-fragment order ----------------
__global__ void prep_w(const float* __restrict__ Wih0, const float* __restrict__ Whh0,
                       const float* __restrict__ Wih1, const float* __restrict__ Whh1,
                       char* __restrict__ ws) {
  int tid = blockIdx.x * 256 + threadIdx.x;       // one u32 = 2 bf16 (j, j+1)
  if (tid >= 7340032) return;
  uint32_t* dst = (uint32_t*)(ws + BFRAG_OFF);
  int layer, wg, ks, lane, jp;
  if (tid < 3145728) { layer = 0; wg = tid / 24576; int rem = tid % 24576; ks = rem >> 8; int r2 = rem & 255; lane = r2 >> 2; jp = r2 & 3; }
  else { int t2 = tid - 3145728; layer = 1; wg = t2 / 32768; int rem = t2 % 32768; ks = rem >> 8; int r2 = rem & 255; lane = r2 >> 2; jp = r2 & 3; }
  int n = lane & 31;
  int row = (n >> 3) * 1024 + wg * 8 + (n & 7);
  int k = ks * 16 + ((lane >> 5) << 3) + jp * 2;
  float w0, w1;
  if (!layer) {   // K = 512 (x via W_ih0) then 1024 (h0 via W_hh0)
    if (k < 512) { w0 = Wih0[row * 512 + k];          w1 = Wih0[row * 512 + k + 1]; }
    else         { w0 = Whh0[row * 1024 + k - 512];   w1 = Whh0[row * 1024 + k - 511]; }
  } else {        // K = 1024 (h0 via W_ih1) then 1024 (h1 via W_hh1)
    if (k < 1024){ w0 = Wih1[row * 1024 + k];         w1 = Wih1[row * 1024 + k + 1]; }
    else         { w0 = Whh1[row * 1024 + k - 1024];  w1 = Whh1[row * 1024 + k - 1023]; }
  }
  dst[tid] = (uint32_t)f2bf(w0) | ((uint32_t)f2bf(w1) << 16);
}

// ---------------- prep: x -> bf16 A-fragment layout, overlaid in c_out[0:16, t, :] ----
__global__ void prep_x(const float* __restrict__ x, float* __restrict__ out) {
  int tid = blockIdx.x * 256 + threadIdx.x;
  if (tid >= 16777216) return;
  int t = tid >> 14;
  int sidx = tid & 16383;
  int jp = sidx & 3;
  int lane = (sidx >> 2) & 63;
  int mtks = sidx >> 8;
  int mt = mtks & 1, ks = mtks >> 1;
  int b = mt * 32 + (lane & 31);
  int k = ks * 16 + ((lane >> 5) << 3) + jp * 2;
  const float* xp = x + ((long)b * S_ + t) * D_ + k;
  uint32_t v = (uint32_t)f2bf(xp[0]) | ((uint32_t)f2bf(xp[1]) << 16);
  ((uint32_t*)(out + COUT_OFF))[(long)(sidx >> 10) * 1048576 + ((long)t << 10) + (sidx & 1023)] = v;
}

// ---------------- main persistent cooperative kernel ----------------
// WGs 0..127: layer0.  WGs 128..255: layer1 (pipelined one step behind).
// B-fragments staged once into LDS; 2x2 wave split; c-state in registers.
// NEW vs R4: NO __threadfence in the loop. Ring publishes are relaxed agent-scope
// atomic stores (write-through to L3); ring reads are relaxed agent-scope atomic
// loads (L2-bypass). Visibility chain: per-thread vmcnt drain at __syncthreads ->
// arrival RMW at L3 -> gen release observed via L3. out/c_out stay cached (lazy
// writeback off the critical path; end-of-kernel flush finalizes).
__global__ void __launch_bounds__(256) lstm_main(float* __restrict__ out, char* __restrict__ ws) {
  extern __shared__ char smem[];
  float (*red)[64][33] = (float (*)[64][33])(smem + BLDS_BYTES);   // [2][64][33]

  const int tid = threadIdx.x;
  const int lane = tid & 63;
  const int wave = tid >> 6;
  const int wg = blockIdx.x;
  const int layer = wg >> 7;
  const int cw = wg & 127;
  const int mt = wave >> 1;   // batch tile: 0 -> rows 0-31, 1 -> rows 32-63
  const int kh = wave & 1;    // K half

  uint32_t* grp_cnt = (uint32_t*)(ws + GRP_OFF + (size_t)(wg >> 5) * 256);
  uint32_t* top_cnt = (uint32_t*)(ws + TOP_OFF);
  uint32_t* bar_gen = (uint32_t*)(ws + GEN_OFF);
  const float* bsum = (const float*)(ws + BSUM_OFF) + layer * G_;
  const char* bwg = ws + (layer ? (B1_OFF + (size_t)cw * B1_PER_WG)
                                : (BFRAG_OFF + (size_t)cw * B0_PER_WG));
  float* coutF = out + COUT_OFF;

  const int ksteps = layer ? 128 : 96;
  const int ksph = ksteps >> 1;        // per-wave K-steps (K half)
  const int khalf = ksph >> 1;         // split into 2 independent MFMA chains

  // ---- stage this WG's B-fragment slice into LDS, once ----
  {
    const int nchunk = ksteps << 6;    // ksteps*1024B / 16B
    for (int i = tid; i < nchunk; i += 256)
      *(bf16x8*)(smem + (size_t)i * 16) = *(const bf16x8*)(bwg + (size_t)i * 16);
  }
  __syncthreads();

  float cst0 = 0.f, cst1 = 0.f;   // cell state: (b=lane, cc=wave) and (b, cc=wave+4)

  for (int t = 0; t <= S_; ++t) {
    if (t) {  // grid barrier #t — no cache-wide fences
      asm volatile("s_waitcnt vmcnt(0)" ::: "memory");  // own sc1 publishes visible at L3
      __syncthreads();
      if (tid == 0) {
        uint32_t prev = __hip_atomic_fetch_add(grp_cnt, 1u, __ATOMIC_RELAXED, __HIP_MEMORY_SCOPE_AGENT);
        if (prev == (uint32_t)(t * 32 - 1)) {     // last of this group's 32 arrivals
          uint32_t p2 = __hip_atomic_fetch_add(top_cnt, 1u, __ATOMIC_RELAXED, __HIP_MEMORY_SCOPE_AGENT);
          if (p2 == (uint32_t)(t * 8 - 1)) {      // last group
            __hip_atomic_store(bar_gen, (uint32_t)t, __ATOMIC_RELAXED, __HIP_MEMORY_SCOPE_AGENT);
          }
        }
        while (__hip_atomic_load(bar_gen, __ATOMIC_RELAXED, __HIP_MEMORY_SCOPE_AGENT) < (uint32_t)t)
          __builtin_amdgcn_s_sleep(1);
        asm volatile("" ::: "memory");
      }
      __syncthreads();
    }
    const bool active = layer ? (t >= 1) : (t < S_);
    if (active) {
      // ring slots: h0[t-1] parity (t-1)&1 ; h1[t-2] parity t&1
      const char* slotH0 = ws + RING_OFF + (size_t)((t - 1) & 1) * SLOT_BYTES;
      const char* slotH1 = ws + RING_OFF + (size_t)(2 + (t & 1)) * SLOT_BYTES;

      f32x16 accA = {}, accB = {};
#pragma unroll 8
      for (int s = 0; s < ksph; ++s) {
        const int ks = kh * ksph + s;
        bf16x8 av;
        if (layer == 0) {
          if (ks < 32) {  // x part from overlay (immutable until after read -> cached load ok)
            int si = ((ks * 2 + mt) * 64 + lane) * 4;
            av = *(const bf16x8*)(coutF + (((long)(si >> 10)) << 20) + ((long)t << 10) + (si & 1023));
          } else {        // h0[t-1]
            int k2 = ks - 32;
            av = ring_ld(slotH0 + ((k2 * 2 + mt) * 64 + lane) * 16);
          }
        } else {
          if (ks < 64) {  // h0[t-1]
            av = ring_ld(slotH0 + ((ks * 2 + mt) * 64 + lane) * 16);
          } else {        // h1[t-2]
            int k2 = ks - 64;
            av = ring_ld(slotH1 + ((k2 * 2 + mt) * 64 + lane) * 16);
          }
        }
        bf16x8 bv = *(const bf16x8*)(smem + (size_t)ks * 1024 + (size_t)lane * 16);
        if (s < khalf) accA = __builtin_amdgcn_mfma_f32_32x32x16_bf16(av, bv, accA, 0, 0, 0);
        else           accB = __builtin_amdgcn_mfma_f32_32x32x16_bf16(av, bv, accB, 0, 0, 0);
      }
      // C/D layout (verified m74/m101): col=lane&31, row=(r&3)+8*(r>>2)+4*(lane>>5)
      const int col = lane & 31;
      const int rbase = 4 * (lane >> 5);
#pragma unroll
      for (int r = 0; r < 16; ++r) {
        int row = (r & 3) + 8 * (r >> 2) + rbase;
        red[kh][mt * 32 + row][col] = accA[r] + accB[r];
      }
      __syncthreads();

      const int b = lane;
      const int bmt = b >> 5;
      char* pub = ws + RING_OFF + (size_t)((layer << 1) + ((layer ? (t - 1) : t) & 1)) * SLOT_BYTES;
#pragma unroll
      for (int r = 0; r < 2; ++r) {
        int cc = wave + 4 * r;
        int hc = cw * 8 + cc;
        float g0 = red[0][b][cc]      + red[1][b][cc]      + bsum[hc];
        float g1 = red[0][b][8 + cc]  + red[1][b][8 + cc]  + bsum[1024 + hc];
        float g2 = red[0][b][16 + cc] + red[1][b][16 + cc] + bsum[2048 + hc];
        float g3 = red[0][b][24 + cc] + red[1][b][24 + cc] + bsum[3072 + hc];
        float cprev = r ? cst1 : cst0;
        float cn = sigf(g1) * cprev + sigf(g0) * tanhf_(g2);
        float hn = sigf(g3) * tanhf_(cn);
        if (r) cst1 = cn; else cst0 = cn;
        // publish h in A-fragment order, write-through (agent-scope relaxed store)
        int ksh = hc >> 4, rem = hc & 15;
        int laned = (b & 31) + ((rem >> 3) << 5);
        pub2(&((uint16_t*)pub)[((ksh * 2 + bmt) * 64 + laned) * 8 + (rem & 7)], f2bf(hn));
        if (layer) {
          long s_ = t - 1;
          long idx = ((long)b << 20) + (s_ << 10) + hc;
          out[idx] = hn;
          out[COUT_OFF + idx] = cn;
          if (s_ == S_ - 1) {
            out[HF_OFF + ((long)b << 10) + hc] = hn;
            out[CF_OFF + ((long)b << 10) + hc] = cn;
          }
        }
      }
    }
  }
}

// ---------------- launch ----------------
extern "C" void kernel_launch(void* const* d_in, const int* in_sizes, int n_in,
                              void* d_out, int out_size, void* d_ws, size_t ws_size,
                              hipStream_t stream) {
  const float* x    = (const float*)d_in[0];
  const float* Wih0 = (const float*)d_in[1];
  const float* Whh0 = (const float*)d_in[2];
  const float* bih0 = (const float*)d_in[3];
  const float* bhh0 = (const float*)d_in[4];
  const float* Wih1 = (const float*)d_in[5];
  const float* Whh1 = (const float*)d_in[6];
  const float* bih1 = (const float*)d_in[7];
  const float* bhh1 = (const float*)d_in[8];
  float* out = (float*)d_out;
  char* ws = (char*)d_ws;

  static bool attr_set = false;
  if (!attr_set) {
    (void)hipFuncSetAttribute((const void*)lstm_main,
                              hipFuncAttributeMaxDynamicSharedMemorySize, SMEM_TOTAL);
    attr_set = true;
  }

  hipLaunchKernelGGL(prep_misc, dim3((140288 + 255) / 256), dim3(256), 0, stream, bih0, bhh0, bih1, bhh1, ws);
  hipLaunchKernelGGL(prep_w,    dim3(7340032 / 256),        dim3(256), 0, stream, Wih0, Whh0, Wih1, Whh1, ws);
  hipLaunchKernelGGL(prep_x,    dim3(16777216 / 256),       dim3(256), 0, stream, x, out);

  void* args[] = { (void*)&out, (void*)&ws };
  hipLaunchCooperativeKernel((void*)lstm_main, dim3(NWG), dim3(256), args, SMEM_TOTAL, stream);
}